// Round 1
// baseline (375.274 us; speedup 1.0000x reference)
//
#include <hip/hip_runtime.h>
#include <stdint.h>

typedef unsigned short u16;
typedef __attribute__((ext_vector_type(8))) __bf16 bf16x8;
typedef __attribute__((ext_vector_type(4))) float f32x4;

#define BSD 6291456   // 4*2048*768
#define WSZ 589824    // 768*768

__device__ __forceinline__ u16 f2bf(float f) {
  union { float f; uint32_t u; } v; v.f = f;
  return (u16)((v.u + 0x7fff + ((v.u >> 16) & 1)) >> 16);
}

__device__ __forceinline__ void load_lds16(const u16* g, u16* l) {
  __builtin_amdgcn_global_load_lds((__attribute__((address_space(1))) void*)(void*)g,
                                   (__attribute__((address_space(3))) void*)l, 16, 0, 0);
}

__device__ __forceinline__ f32x4 mfma16(bf16x8 a, bf16x8 b, f32x4 c) {
  return __builtin_amdgcn_mfma_f32_16x16x32_bf16(a, b, c, 0, 0, 0);
}

// ---------------- fp32 -> bf16 conversion of q,k,v + 4 weights ----------------
__global__ void convert_all(const float* __restrict__ q, const float* __restrict__ k,
                            const float* __restrict__ v, const float* __restrict__ wq,
                            const float* __restrict__ wk, const float* __restrict__ wv,
                            const float* __restrict__ wd, u16* __restrict__ ws) {
  long e = ((long)blockIdx.x * blockDim.x + threadIdx.x) * 8;
  const float* src;
  if (e < (long)BSD) src = q + e;
  else if (e < 2L*BSD) src = k + (e - (long)BSD);
  else if (e < 3L*BSD) src = v + (e - 2L*BSD);
  else {
    long r = e - 3L*BSD;
    if (r < (long)WSZ) src = wq + r;
    else if (r < 2L*WSZ) src = wk + (r - (long)WSZ);
    else if (r < 3L*WSZ) src = wv + (r - 2L*WSZ);
    else src = wd + (r - 3L*WSZ);
  }
  float4 f0 = ((const float4*)src)[0];
  float4 f1 = ((const float4*)src)[1];
  union { u16 s[8]; uint4 u; } o;
  o.s[0]=f2bf(f0.x); o.s[1]=f2bf(f0.y); o.s[2]=f2bf(f0.z); o.s[3]=f2bf(f0.w);
  o.s[4]=f2bf(f1.x); o.s[5]=f2bf(f1.y); o.s[6]=f2bf(f1.z); o.s[7]=f2bf(f1.w);
  *(uint4*)(ws + e) = o.u;
}

// ---------------- C = A @ B^T  (A[M,K], B[N,K] bf16; m97-style 128x128xBK32) ----------------
template<int OUTF32>
__global__ __launch_bounds__(256) void gemm_bt(const u16* __restrict__ A, const u16* __restrict__ Bm,
                                               u16* __restrict__ Cb, float* __restrict__ Cf,
                                               const float* __restrict__ bias, int M, int N, int K) {
  __shared__ u16 ldsA[128*32];
  __shared__ u16 ldsB[128*32];
  const int t = threadIdx.x, w = t >> 6, lane = t & 63, quad = lane >> 4, n16 = lane & 15;
  const int m0 = blockIdx.x * 128, n0 = blockIdx.y * 128;
  const int wr = (w >> 1) * 64, wc = (w & 1) * 64;
  f32x4 acc[4][4] = {};
  for (int k0 = 0; k0 < K; k0 += 32) {
    __syncthreads();
#pragma unroll
    for (int j = 0; j < 2; ++j) {
      int slot = j*256 + w*64 + lane;        // lane-linear LDS dst (wave-uniform base + lane*16)
      int row = slot >> 2, ch = slot & 3;
      load_lds16(A  + (size_t)(m0 + row)*K + k0 + ch*8, ldsA + slot*8);
      load_lds16(Bm + (size_t)(n0 + row)*K + k0 + ch*8, ldsB + slot*8);
    }
    __syncthreads();
    bf16x8 af[4], bf[4];
#pragma unroll
    for (int i = 0; i < 4; ++i) {
      af[i] = *(const bf16x8*)(ldsA + (wr + i*16 + n16)*32 + quad*8);
      bf[i] = *(const bf16x8*)(ldsB + (wc + i*16 + n16)*32 + quad*8);
    }
#pragma unroll
    for (int mi = 0; mi < 4; ++mi)
#pragma unroll
      for (int ni = 0; ni < 4; ++ni)
        acc[mi][ni] = mfma16(af[mi], bf[ni], acc[mi][ni]);
  }
#pragma unroll
  for (int mi = 0; mi < 4; ++mi)
#pragma unroll
    for (int ni = 0; ni < 4; ++ni)
#pragma unroll
      for (int i = 0; i < 4; ++i) {
        size_t r = (size_t)m0 + wr + mi*16 + quad*4 + i;   // C/D: row=(lane>>4)*4+i
        size_t c = (size_t)n0 + wc + ni*16 + n16;          //      col=lane&15
        float val = acc[mi][ni][i];
        if (OUTF32) Cf[r*(size_t)N + c] = val + bias[c];
        else        Cb[r*(size_t)N + c] = f2bf(val);
      }
}

// ---------------- V [B*S,768] -> Vt [B,H,64,S] ----------------
__global__ __launch_bounds__(256) void transpose_v(const u16* __restrict__ Vh, u16* __restrict__ Vt) {
  __shared__ u16 tile[64][72];  // +8 pad breaks bank aliasing
  const int b = blockIdx.z, h = blockIdx.y, st = blockIdx.x;
  const int t = threadIdx.x;
#pragma unroll
  for (int i = 0; i < 16; ++i) {
    int e = i*256 + t;
    int s = e >> 6, d = e & 63;
    tile[s][d] = Vh[(size_t)(b*2048 + st*64 + s)*768 + h*64 + d];
  }
  __syncthreads();
#pragma unroll
  for (int i = 0; i < 16; ++i) {
    int e = i*256 + t;
    int d = e >> 6, s = e & 63;
    Vt[((size_t)(b*12 + h)*64 + d)*2048 + st*64 + s] = tile[s][d];
  }
}

// ---------------- fused attention: flash pass, no max-subtraction (|logit| < ~7) ----------------
__global__ __launch_bounds__(256) void attn_fused(const u16* __restrict__ Qh, const u16* __restrict__ Kh,
                                                  const u16* __restrict__ Vt, u16* __restrict__ ctx,
                                                  float* __restrict__ rowsum) {
  __shared__ u16 ldsK[128*64];   // [n][8 chunks of 8] chunk-XOR-swizzled
  __shared__ u16 ldsV[64*128];   // [d][16 chunks]     chunk-XOR-swizzled
  __shared__ u16 ldsP[128*128];  // [m][16 chunks]     chunk-XOR-swizzled
  const int qt = blockIdx.x, h = blockIdx.y, b = blockIdx.z;
  const int t = threadIdx.x, w = t >> 6, lane = t & 63, quad = lane >> 4, n16 = lane & 15;
  const int q0 = qt * 128;
  const u16* Kbh = Kh + (size_t)b*2048*768 + h*64;
  const u16* Vbh = Vt + (size_t)(b*12 + h)*64*2048;
  bf16x8 qf[2][2];               // Q A-frags kept in registers for the whole block
#pragma unroll
  for (int mi = 0; mi < 2; ++mi)
#pragma unroll
    for (int ks = 0; ks < 2; ++ks)
      qf[mi][ks] = *(const bf16x8*)(Qh + (size_t)(b*2048 + q0 + w*32 + mi*16 + n16)*768
                                       + h*64 + ks*32 + quad*8);
  f32x4 oacc[2][4] = {};
  float rs[2][4] = {};
#pragma unroll 1
  for (int c = 0; c < 16; ++c) {
    __syncthreads();                      // prior chunk's LDS reads drained
#pragma unroll
    for (int j = 0; j < 4; ++j) {
      int slot = j*256 + w*64 + lane;     // lane-linear LDS slots
      { int n = slot >> 3, cs = slot & 7, cg = cs ^ (n & 7);
        load_lds16(Kbh + (size_t)(c*128 + n)*768 + cg*8, ldsK + slot*8); }
      { int d = slot >> 4, cs = slot & 15, cg = cs ^ (d & 15);
        load_lds16(Vbh + (size_t)d*2048 + c*128 + cg*8, ldsV + slot*8); }
    }
    __syncthreads();                      // tiles ready (drains vmcnt)
    f32x4 sacc[2][8] = {};
#pragma unroll
    for (int ni = 0; ni < 8; ++ni) {
      int n = ni*16 + n16;
      bf16x8 kf0 = *(const bf16x8*)(ldsK + n*64 + ((quad)     ^ (n & 7))*8);
      bf16x8 kf1 = *(const bf16x8*)(ldsK + n*64 + ((4 + quad) ^ (n & 7))*8);
#pragma unroll
      for (int mi = 0; mi < 2; ++mi) {
        sacc[mi][ni] = mfma16(qf[mi][0], kf0, sacc[mi][ni]);
        sacc[mi][ni] = mfma16(qf[mi][1], kf1, sacc[mi][ni]);
      }
    }
    // softmax numerators + P -> LDS (C-layout -> A-layout round trip, m120)
#pragma unroll
    for (int mi = 0; mi < 2; ++mi)
#pragma unroll
      for (int ni = 0; ni < 8; ++ni)
#pragma unroll
        for (int i = 0; i < 4; ++i) {
          float p = __expf(sacc[mi][ni][i] * 0.125f);
          rs[mi][i] += p;
          int m = w*32 + mi*16 + quad*4 + i;
          int n = ni*16 + n16;
          ldsP[m*128 + (((n >> 3) ^ (m & 7)) * 8) + (n & 7)] = f2bf(p);
        }
    __syncthreads();                      // P visible
#pragma unroll
    for (int ks = 0; ks < 4; ++ks) {
      bf16x8 pf[2], vf[4];
#pragma unroll
      for (int mi = 0; mi < 2; ++mi) {
        int m = w*32 + mi*16 + n16;
        pf[mi] = *(const bf16x8*)(ldsP + m*128 + (((ks*4 + quad) ^ (m & 7)) * 8));
      }
#pragma unroll
      for (int di = 0; di < 4; ++di) {
        int n = di*16 + n16;
        vf[di] = *(const bf16x8*)(ldsV + n*128 + (((ks*4 + quad) ^ (n & 15)) * 8));
      }
#pragma unroll
      for (int mi = 0; mi < 2; ++mi)
#pragma unroll
        for (int di = 0; di < 4; ++di)
          oacc[mi][di] = mfma16(pf[mi], vf[di], oacc[mi][di]);
    }
  }
  // reduce row sums across the 16 column-lanes
#pragma unroll
  for (int mi = 0; mi < 2; ++mi)
#pragma unroll
    for (int i = 0; i < 4; ++i) {
      float s = rs[mi][i];
      s += __shfl_xor(s, 1); s += __shfl_xor(s, 2);
      s += __shfl_xor(s, 4); s += __shfl_xor(s, 8);
      rs[mi][i] = s;
    }
#pragma unroll
  for (int mi = 0; mi < 2; ++mi)
#pragma unroll
    for (int di = 0; di < 4; ++di)
#pragma unroll
      for (int i = 0; i < 4; ++i) {
        size_t r = (size_t)b*2048 + q0 + w*32 + mi*16 + quad*4 + i;
        int cc = h*64 + di*16 + n16;
        ctx[r*768 + cc] = f2bf(oacc[mi][di][i] / rs[mi][i]);
      }
  if (h == 0 && n16 == 0) {
#pragma unroll
    for (int mi = 0; mi < 2; ++mi)
#pragma unroll
      for (int i = 0; i < 4; ++i)
        rowsum[b*2048 + q0 + w*32 + mi*16 + quad*4 + i] = rs[mi][i];
  }
}

// ---------------- attn[:,0,:,:] writer: recompute QK^T for h=0, scale by 1/rowsum ----------------
__global__ __launch_bounds__(256) void attn_h0(const u16* __restrict__ Qh, const u16* __restrict__ Kh,
                                               const float* __restrict__ rowsum, float* __restrict__ aout) {
  __shared__ u16 ldsK[128*64];
  const int qt = blockIdx.x, kt = blockIdx.y, b = blockIdx.z;
  const int t = threadIdx.x, w = t >> 6, lane = t & 63, quad = lane >> 4, n16 = lane & 15;
  const int q0 = qt * 128;
  const u16* Kbh = Kh + (size_t)b*2048*768;  // h = 0
  bf16x8 qf[2][2];
#pragma unroll
  for (int mi = 0; mi < 2; ++mi)
#pragma unroll
    for (int ks = 0; ks < 2; ++ks)
      qf[mi][ks] = *(const bf16x8*)(Qh + (size_t)(b*2048 + q0 + w*32 + mi*16 + n16)*768
                                       + ks*32 + quad*8);
#pragma unroll
  for (int j = 0; j < 4; ++j) {
    int slot = j*256 + w*64 + lane;
    int n = slot >> 3, cs = slot & 7, cg = cs ^ (n & 7);
    load_lds16(Kbh + (size_t)(kt*128 + n)*768 + cg*8, ldsK + slot*8);
  }
  __syncthreads();
  f32x4 sacc[2][8] = {};
#pragma unroll
  for (int ni = 0; ni < 8; ++ni) {
    int n = ni*16 + n16;
    bf16x8 kf0 = *(const bf16x8*)(ldsK + n*64 + ((quad)     ^ (n & 7))*8);
    bf16x8 kf1 = *(const bf16x8*)(ldsK + n*64 + ((4 + quad) ^ (n & 7))*8);
#pragma unroll
    for (int mi = 0; mi < 2; ++mi) {
      sacc[mi][ni] = mfma16(qf[mi][0], kf0, sacc[mi][ni]);
      sacc[mi][ni] = mfma16(qf[mi][1], kf1, sacc[mi][ni]);
    }
  }
  float inv[2][4];
#pragma unroll
  for (int mi = 0; mi < 2; ++mi)
#pragma unroll
    for (int i = 0; i < 4; ++i)
      inv[mi][i] = 1.0f / rowsum[b*2048 + q0 + w*32 + mi*16 + quad*4 + i];
#pragma unroll
  for (int mi = 0; mi < 2; ++mi)
#pragma unroll
    for (int ni = 0; ni < 8; ++ni)
#pragma unroll
      for (int i = 0; i < 4; ++i) {
        size_t r = (size_t)b*2048 + q0 + w*32 + mi*16 + quad*4 + i;
        size_t cc = (size_t)kt*128 + ni*16 + n16;
        aout[r*2048 + cc] = __expf(sacc[mi][ni][i] * 0.125f) * inv[mi][i];
      }
}

extern "C" void kernel_launch(void* const* d_in, const int* in_sizes, int n_in,
                              void* d_out, int out_size, void* d_ws, size_t ws_size,
                              hipStream_t stream) {
  (void)in_sizes; (void)n_in; (void)out_size; (void)ws_size;
  const float* q  = (const float*)d_in[0];
  const float* k  = (const float*)d_in[1];
  const float* v  = (const float*)d_in[2];
  const float* wq = (const float*)d_in[3];
  const float* wk = (const float*)d_in[4];
  const float* wv = (const float*)d_in[5];
  const float* wd = (const float*)d_in[6];
  const float* bd = (const float*)d_in[7];

  // ws layout (u16 elements); aliasing exploits producer/consumer ordering:
  //   qb [BSD] -> later Vt [B,H,64,S]    (qb dead after Q projection)
  //   kb [BSD] -> later Vh [B*S,768]     (kb dead after K projection)
  //   vb [BSD] -> later ctx [B*S,768]    (vb dead after V projection)
  u16* ws  = (u16*)d_ws;
  u16* qb  = ws;
  u16* kb  = ws + (size_t)BSD;
  u16* vb  = ws + 2L*BSD;
  u16* wqb = ws + 3L*BSD;
  u16* wkb = wqb + WSZ;
  u16* wvb = wqb + 2L*WSZ;
  u16* wdb = wqb + 3L*WSZ;
  u16* Qh  = ws + 3L*BSD + 4L*WSZ;
  u16* Kh  = Qh + (size_t)BSD;
  float* rsum = (float*)(Kh + (size_t)BSD);   // 8192 floats; total ws use ~67.7 MB
  u16* Vh  = kb;
  u16* Vt  = qb;
  u16* ctx = vb;
  float* out  = (float*)d_out;
  float* aout = out + (size_t)BSD;

  convert_all<<<dim3(10368), 256, 0, stream>>>(q, k, v, wq, wk, wv, wd, ws);
  dim3 gp(64, 6);
  gemm_bt<0><<<gp, 256, 0, stream>>>(qb, wqb, Qh, nullptr, nullptr, 8192, 768, 768);
  gemm_bt<0><<<gp, 256, 0, stream>>>(kb, wkb, Kh, nullptr, nullptr, 8192, 768, 768);
  gemm_bt<0><<<gp, 256, 0, stream>>>(vb, wvb, Vh, nullptr, nullptr, 8192, 768, 768);
  transpose_v<<<dim3(32, 12, 4), 256, 0, stream>>>(Vh, Vt);
  attn_fused<<<dim3(16, 12, 4), 256, 0, stream>>>(Qh, Kh, Vt, ctx, rsum);
  attn_h0<<<dim3(16, 16, 4), 256, 0, stream>>>(Qh, Kh, rsum, aout);
  gemm_bt<1><<<gp, 256, 0, stream>>>(ctx, wdb, nullptr, out, bd, 8192, 768, 768);
}

// Round 2
// 366.045 us; speedup vs baseline: 1.0252x; 1.0252x over previous
//
#include <hip/hip_runtime.h>
#include <stdint.h>

typedef unsigned short u16;
typedef __attribute__((ext_vector_type(8))) __bf16 bf16x8;
typedef __attribute__((ext_vector_type(4))) float f32x4;

#define BSD 6291456   // 4*2048*768
#define WSZ 589824    // 768*768

__device__ __forceinline__ u16 f2bf(float f) {
  union { float f; uint32_t u; } v; v.f = f;
  return (u16)((v.u + 0x7fff + ((v.u >> 16) & 1)) >> 16);
}

__device__ __forceinline__ void load_lds16(const u16* g, u16* l) {
  __builtin_amdgcn_global_load_lds((__attribute__((address_space(1))) void*)(void*)g,
                                   (__attribute__((address_space(3))) void*)l, 16, 0, 0);
}

__device__ __forceinline__ f32x4 mfma16(bf16x8 a, bf16x8 b, f32x4 c) {
  return __builtin_amdgcn_mfma_f32_16x16x32_bf16(a, b, c, 0, 0, 0);
}

// ---------------- fp32 -> bf16 conversion of q,k,v + 4 weights ----------------
__global__ void convert_all(const float* __restrict__ q, const float* __restrict__ k,
                            const float* __restrict__ v, const float* __restrict__ wq,
                            const float* __restrict__ wk, const float* __restrict__ wv,
                            const float* __restrict__ wd, u16* __restrict__ ws) {
  long e = ((long)blockIdx.x * blockDim.x + threadIdx.x) * 8;
  const float* src;
  if (e < (long)BSD) src = q + e;
  else if (e < 2L*BSD) src = k + (e - (long)BSD);
  else if (e < 3L*BSD) src = v + (e - 2L*BSD);
  else {
    long r = e - 3L*BSD;
    if (r < (long)WSZ) src = wq + r;
    else if (r < 2L*WSZ) src = wk + (r - (long)WSZ);
    else if (r < 3L*WSZ) src = wv + (r - 2L*WSZ);
    else src = wd + (r - 3L*WSZ);
  }
  float4 f0 = ((const float4*)src)[0];
  float4 f1 = ((const float4*)src)[1];
  union { u16 s[8]; uint4 u; } o;
  o.s[0]=f2bf(f0.x); o.s[1]=f2bf(f0.y); o.s[2]=f2bf(f0.z); o.s[3]=f2bf(f0.w);
  o.s[4]=f2bf(f1.x); o.s[5]=f2bf(f1.y); o.s[6]=f2bf(f1.z); o.s[7]=f2bf(f1.w);
  *(uint4*)(ws + e) = o.u;
}

// ---------------- C = A @ B^T  (A[M,K], B[N,K] bf16; m97-style 128x128xBK32) ----------------
template<int OUTF32>
__global__ __launch_bounds__(256) void gemm_bt(const u16* __restrict__ A, const u16* __restrict__ Bm,
                                               u16* __restrict__ Cb, float* __restrict__ Cf,
                                               const float* __restrict__ bias, int M, int N, int K) {
  __shared__ u16 ldsA[128*32];
  __shared__ u16 ldsB[128*32];
  const int t = threadIdx.x, w = t >> 6, lane = t & 63, quad = lane >> 4, n16 = lane & 15;
  const int m0 = blockIdx.x * 128, n0 = blockIdx.y * 128;
  const int wr = (w >> 1) * 64, wc = (w & 1) * 64;
  f32x4 acc[4][4] = {};
  for (int k0 = 0; k0 < K; k0 += 32) {
    __syncthreads();
#pragma unroll
    for (int j = 0; j < 2; ++j) {
      int slot = j*256 + w*64 + lane;        // lane-linear LDS dst (wave-uniform base + lane*16)
      int row = slot >> 2, ch = slot & 3;
      load_lds16(A  + (size_t)(m0 + row)*K + k0 + ch*8, ldsA + slot*8);
      load_lds16(Bm + (size_t)(n0 + row)*K + k0 + ch*8, ldsB + slot*8);
    }
    __syncthreads();
    bf16x8 af[4], bf[4];
#pragma unroll
    for (int i = 0; i < 4; ++i) {
      af[i] = *(const bf16x8*)(ldsA + (wr + i*16 + n16)*32 + quad*8);
      bf[i] = *(const bf16x8*)(ldsB + (wc + i*16 + n16)*32 + quad*8);
    }
#pragma unroll
    for (int mi = 0; mi < 4; ++mi)
#pragma unroll
      for (int ni = 0; ni < 4; ++ni)
        acc[mi][ni] = mfma16(af[mi], bf[ni], acc[mi][ni]);
  }
#pragma unroll
  for (int mi = 0; mi < 4; ++mi)
#pragma unroll
    for (int ni = 0; ni < 4; ++ni)
#pragma unroll
      for (int i = 0; i < 4; ++i) {
        size_t r = (size_t)m0 + wr + mi*16 + quad*4 + i;   // C/D: row=(lane>>4)*4+i
        size_t c = (size_t)n0 + wc + ni*16 + n16;          //      col=lane&15
        float val = acc[mi][ni][i];
        if (OUTF32) Cf[r*(size_t)N + c] = val + bias[c];
        else        Cb[r*(size_t)N + c] = f2bf(val);
      }
}

// ---------------- V [B*S,768] -> Vt [B,H,64,S] ----------------
__global__ __launch_bounds__(256) void transpose_v(const u16* __restrict__ Vh, u16* __restrict__ Vt) {
  __shared__ u16 tile[64][72];  // +8 pad breaks bank aliasing
  const int b = blockIdx.z, h = blockIdx.y, st = blockIdx.x;
  const int t = threadIdx.x;
#pragma unroll
  for (int i = 0; i < 16; ++i) {
    int e = i*256 + t;
    int s = e >> 6, d = e & 63;
    tile[s][d] = Vh[(size_t)(b*2048 + st*64 + s)*768 + h*64 + d];
  }
  __syncthreads();
#pragma unroll
  for (int i = 0; i < 16; ++i) {
    int e = i*256 + t;
    int d = e >> 6, s = e & 63;
    Vt[((size_t)(b*12 + h)*64 + d)*2048 + st*64 + s] = tile[s][d];
  }
}

// ---------------- fused attention, round 2 restructure ----------------
// Computes S^T = K.Q^T per tile (operand swap; A/B frag layouts are identical so
// the Q/K fragment reads are unchanged). S^T C-layout gives each lane 4
// CONSECUTIVE n for a fixed m -> P stored row-major with packed ds_write_b64,
// ldsP is wave-private (no barrier), and PV reads P in A-layout as ds_read_b128.
// 64-key chunks -> 32KB LDS -> 4 blocks/CU (vs 2 before).
__global__ __launch_bounds__(256, 4) void attn_fused(const u16* __restrict__ Qh, const u16* __restrict__ Kh,
                                                     const u16* __restrict__ Vt, u16* __restrict__ ctx,
                                                     float* __restrict__ rowsum) {
  __shared__ u16 ldsK[64*64];    // [n][8 chunks of 8 u16], chunk XOR-swizzled by n&7
  __shared__ u16 ldsV[64*64];    // [d][8 chunks],          swizzled by d&7
  __shared__ u16 ldsP[128*64];   // [m][8 b128-chunks],     swizzled by m&7; wave-private rows
  const int qt = blockIdx.x, h = blockIdx.y, b = blockIdx.z;
  const int t = threadIdx.x, w = t >> 6, lane = t & 63, quad = lane >> 4, n16 = lane & 15;
  const int q0 = qt * 128;
  const int sw = n16 & 7;        // xor-swizzle key (== m&7 == n&7 == d&7 for this lane's rows)
  const u16* Kbh = Kh + (size_t)b*2048*768 + h*64;
  const u16* Vbh = Vt + (size_t)(b*12 + h)*64*2048;
  bf16x8 qf[2][2];               // Q B-frags (same layout as A-frags) in registers all kernel
#pragma unroll
  for (int mi = 0; mi < 2; ++mi)
#pragma unroll
    for (int ks = 0; ks < 2; ++ks)
      qf[mi][ks] = *(const bf16x8*)(Qh + (size_t)(b*2048 + q0 + w*32 + mi*16 + n16)*768
                                       + h*64 + ks*32 + quad*8);
  f32x4 oacc[2][4] = {};
  float rs[2] = {};
  const float escale = 0.18033688f;   // log2(e)/8
#pragma unroll 1
  for (int c = 0; c < 32; ++c) {
    __syncthreads();                  // prior chunk's ldsK/ldsV reads drained
#pragma unroll
    for (int j = 0; j < 2; ++j) {
      int slot = j*256 + t;           // lane-linear LDS dst
      int n = slot >> 3, cg = (slot & 7) ^ (n & 7);
      load_lds16(Kbh + (size_t)(c*64 + n)*768 + cg*8, ldsK + slot*8);
      load_lds16(Vbh + (size_t)n*2048 + c*64 + cg*8, ldsV + slot*8);
    }
    __syncthreads();                  // tiles ready (drains vmcnt)
    f32x4 sacc[4][2] = {};
#pragma unroll
    for (int ni = 0; ni < 4; ++ni) {
      const u16* krow = ldsK + (ni*16 + n16)*64;
      bf16x8 kf0 = *(const bf16x8*)(krow + ((0 + quad) ^ sw)*8);
      bf16x8 kf1 = *(const bf16x8*)(krow + ((4 + quad) ^ sw)*8);
#pragma unroll
      for (int mi = 0; mi < 2; ++mi) {
        sacc[ni][mi] = mfma16(kf0, qf[mi][0], sacc[ni][mi]);   // S^T = K.Q^T
        sacc[ni][mi] = mfma16(kf1, qf[mi][1], sacc[ni][mi]);
      }
    }
    // exp + packed P store: lane holds n = ni*16+quad*4+{0..3} for m = w*32+mi*16+n16
#pragma unroll
    for (int mi = 0; mi < 2; ++mi) {
      int m = w*32 + mi*16 + n16;
      u16* prow = ldsP + m*64 + (quad & 1)*4;
#pragma unroll
      for (int ni = 0; ni < 4; ++ni) {
        float p0 = exp2f(sacc[ni][mi][0] * escale);
        float p1 = exp2f(sacc[ni][mi][1] * escale);
        float p2 = exp2f(sacc[ni][mi][2] * escale);
        float p3 = exp2f(sacc[ni][mi][3] * escale);
        rs[mi] += (p0 + p1) + (p2 + p3);
        uint2 pk;
        pk.x = (uint32_t)f2bf(p0) | ((uint32_t)f2bf(p1) << 16);
        pk.y = (uint32_t)f2bf(p2) | ((uint32_t)f2bf(p3) << 16);
        int c128 = ((ni*2 + (quad >> 1)) ^ sw);
        *(uint2*)(prow + c128*8) = pk;
      }
    }
    // PV: A = P (wave-private LDS rows), B = V^T chunk. No barrier needed.
#pragma unroll
    for (int kt = 0; kt < 2; ++kt) {
      bf16x8 pf[2], vf[4];
#pragma unroll
      for (int mi = 0; mi < 2; ++mi)
        pf[mi] = *(const bf16x8*)(ldsP + (w*32 + mi*16 + n16)*64 + ((kt*4 + quad) ^ sw)*8);
#pragma unroll
      for (int di = 0; di < 4; ++di)
        vf[di] = *(const bf16x8*)(ldsV + (di*16 + n16)*64 + ((kt*4 + quad) ^ sw)*8);
#pragma unroll
      for (int mi = 0; mi < 2; ++mi)
#pragma unroll
        for (int di = 0; di < 4; ++di)
          oacc[mi][di] = mfma16(pf[mi], vf[di], oacc[mi][di]);
    }
  }
  // full row sums: reduce across the 4 quads (lanes sharing n16)
#pragma unroll
  for (int mi = 0; mi < 2; ++mi) {
    float s = rs[mi];
    s += __shfl_xor(s, 16);
    s += __shfl_xor(s, 32);
    rs[mi] = s;
  }
  // redistribute: oacc C-layout rows are quad*4+i; rowsum lives at lane n16==row
  float invr[2][4];
#pragma unroll
  for (int mi = 0; mi < 2; ++mi)
#pragma unroll
    for (int i = 0; i < 4; ++i)
      invr[mi][i] = 1.0f / __shfl(rs[mi], (lane & 48) | (quad*4 + i));
#pragma unroll
  for (int mi = 0; mi < 2; ++mi)
#pragma unroll
    for (int di = 0; di < 4; ++di)
#pragma unroll
      for (int i = 0; i < 4; ++i) {
        size_t r = (size_t)b*2048 + q0 + w*32 + mi*16 + quad*4 + i;
        int cc = h*64 + di*16 + n16;
        ctx[r*768 + cc] = f2bf(oacc[mi][di][i] * invr[mi][i]);
      }
  if (h == 0 && quad == 0) {
#pragma unroll
    for (int mi = 0; mi < 2; ++mi)
      rowsum[b*2048 + q0 + w*32 + mi*16 + n16] = rs[mi];
  }
}

// ---------------- attn[:,0,:,:] writer: recompute QK^T for h=0, scale by 1/rowsum ----------------
__global__ __launch_bounds__(256) void attn_h0(const u16* __restrict__ Qh, const u16* __restrict__ Kh,
                                               const float* __restrict__ rowsum, float* __restrict__ aout) {
  __shared__ u16 ldsK[128*64];
  const int qt = blockIdx.x, kt = blockIdx.y, b = blockIdx.z;
  const int t = threadIdx.x, w = t >> 6, lane = t & 63, quad = lane >> 4, n16 = lane & 15;
  const int q0 = qt * 128;
  const u16* Kbh = Kh + (size_t)b*2048*768;  // h = 0
  bf16x8 qf[2][2];
#pragma unroll
  for (int mi = 0; mi < 2; ++mi)
#pragma unroll
    for (int ks = 0; ks < 2; ++ks)
      qf[mi][ks] = *(const bf16x8*)(Qh + (size_t)(b*2048 + q0 + w*32 + mi*16 + n16)*768
                                       + ks*32 + quad*8);
#pragma unroll
  for (int j = 0; j < 4; ++j) {
    int slot = j*256 + w*64 + lane;
    int n = slot >> 3, cs = slot & 7, cg = cs ^ (n & 7);
    load_lds16(Kbh + (size_t)(kt*128 + n)*768 + cg*8, ldsK + slot*8);
  }
  __syncthreads();
  f32x4 sacc[2][8] = {};
#pragma unroll
  for (int ni = 0; ni < 8; ++ni) {
    int n = ni*16 + n16;
    bf16x8 kf0 = *(const bf16x8*)(ldsK + n*64 + ((quad)     ^ (n & 7))*8);
    bf16x8 kf1 = *(const bf16x8*)(ldsK + n*64 + ((4 + quad) ^ (n & 7))*8);
#pragma unroll
    for (int mi = 0; mi < 2; ++mi) {
      sacc[mi][ni] = mfma16(qf[mi][0], kf0, sacc[mi][ni]);
      sacc[mi][ni] = mfma16(qf[mi][1], kf1, sacc[mi][ni]);
    }
  }
  float inv[2][4];
#pragma unroll
  for (int mi = 0; mi < 2; ++mi)
#pragma unroll
    for (int i = 0; i < 4; ++i)
      inv[mi][i] = 1.0f / rowsum[b*2048 + q0 + w*32 + mi*16 + quad*4 + i];
#pragma unroll
  for (int mi = 0; mi < 2; ++mi)
#pragma unroll
    for (int ni = 0; ni < 8; ++ni)
#pragma unroll
      for (int i = 0; i < 4; ++i) {
        size_t r = (size_t)b*2048 + q0 + w*32 + mi*16 + quad*4 + i;
        size_t cc = (size_t)kt*128 + ni*16 + n16;
        aout[r*2048 + cc] = __expf(sacc[mi][ni][i] * 0.125f) * inv[mi][i];
      }
}

extern "C" void kernel_launch(void* const* d_in, const int* in_sizes, int n_in,
                              void* d_out, int out_size, void* d_ws, size_t ws_size,
                              hipStream_t stream) {
  (void)in_sizes; (void)n_in; (void)out_size; (void)ws_size;
  const float* q  = (const float*)d_in[0];
  const float* k  = (const float*)d_in[1];
  const float* v  = (const float*)d_in[2];
  const float* wq = (const float*)d_in[3];
  const float* wk = (const float*)d_in[4];
  const float* wv = (const float*)d_in[5];
  const float* wd = (const float*)d_in[6];
  const float* bd = (const float*)d_in[7];

  // ws layout (u16 elements); aliasing exploits producer/consumer ordering:
  //   qb [BSD] -> later Vt [B,H,64,S]    (qb dead after Q projection)
  //   kb [BSD] -> later Vh [B*S,768]     (kb dead after K projection)
  //   vb [BSD] -> later ctx [B*S,768]    (vb dead after V projection)
  u16* ws  = (u16*)d_ws;
  u16* qb  = ws;
  u16* kb  = ws + (size_t)BSD;
  u16* vb  = ws + 2L*BSD;
  u16* wqb = ws + 3L*BSD;
  u16* wkb = wqb + WSZ;
  u16* wvb = wqb + 2L*WSZ;
  u16* wdb = wqb + 3L*WSZ;
  u16* Qh  = ws + 3L*BSD + 4L*WSZ;
  u16* Kh  = Qh + (size_t)BSD;
  float* rsum = (float*)(Kh + (size_t)BSD);   // 8192 floats; total ws use ~67.7 MB
  u16* Vh  = kb;
  u16* Vt  = qb;
  u16* ctx = vb;
  float* out  = (float*)d_out;
  float* aout = out + (size_t)BSD;

  convert_all<<<dim3(10368), 256, 0, stream>>>(q, k, v, wq, wk, wv, wd, ws);
  dim3 gp(64, 6);
  gemm_bt<0><<<gp, 256, 0, stream>>>(qb, wqb, Qh, nullptr, nullptr, 8192, 768, 768);
  gemm_bt<0><<<gp, 256, 0, stream>>>(kb, wkb, Kh, nullptr, nullptr, 8192, 768, 768);
  gemm_bt<0><<<gp, 256, 0, stream>>>(vb, wvb, Vh, nullptr, nullptr, 8192, 768, 768);
  transpose_v<<<dim3(32, 12, 4), 256, 0, stream>>>(Vh, Vt);
  attn_fused<<<dim3(16, 12, 4), 256, 0, stream>>>(Qh, Kh, Vt, ctx, rsum);
  attn_h0<<<dim3(16, 16, 4), 256, 0, stream>>>(Qh, Kh, rsum, aout);
  gemm_bt<1><<<gp, 256, 0, stream>>>(ctx, wdb, nullptr, out, bd, 8192, 768, 768);
}

// Round 3
// 322.891 us; speedup vs baseline: 1.1622x; 1.1336x over previous
//
#include <hip/hip_runtime.h>
#include <stdint.h>

typedef unsigned short u16;
typedef __attribute__((ext_vector_type(8))) __bf16 bf16x8;
typedef __attribute__((ext_vector_type(4))) float f32x4;

#define BSD 6291456   // 4*2048*768
#define WSZ 589824    // 768*768
#define QSCALE 0.18033688011112042f   // log2(e)/8, folded into Q projection

#if __has_builtin(__builtin_amdgcn_exp2f)
#define EXP2(x) __builtin_amdgcn_exp2f(x)
#else
#define EXP2(x) __builtin_exp2f(x)
#endif

__device__ __forceinline__ uint32_t fbits(float f) {
  union { float f; uint32_t u; } v; v.f = f; return v.u;
}
__device__ __forceinline__ u16 f2bf(float f) {           // RNE (epilogue scalar use only)
  uint32_t u = fbits(f);
  return (u16)((u + 0x7fff + ((u >> 16) & 1)) >> 16);
}
// round-to-nearest (half-up) bf16 pack of two floats via v_perm_b32: 3 insts / 2 values
__device__ __forceinline__ uint32_t pack_bf16rn(float lo, float hi) {
  return __builtin_amdgcn_perm(fbits(hi) + 0x8000u, fbits(lo) + 0x8000u, 0x07060302u);
}

__device__ __forceinline__ void load_lds16(const u16* g, u16* l) {
  __builtin_amdgcn_global_load_lds((__attribute__((address_space(1))) void*)(void*)g,
                                   (__attribute__((address_space(3))) void*)l, 16, 0, 0);
}

__device__ __forceinline__ f32x4 mfma16(bf16x8 a, bf16x8 b, f32x4 c) {
  return __builtin_amdgcn_mfma_f32_16x16x32_bf16(a, b, c, 0, 0, 0);
}

// ---------------- fp32 -> bf16 conversion of q,k,v + 4 weights ----------------
__global__ void convert_all(const float* __restrict__ q, const float* __restrict__ k,
                            const float* __restrict__ v, const float* __restrict__ wq,
                            const float* __restrict__ wk, const float* __restrict__ wv,
                            const float* __restrict__ wd, u16* __restrict__ ws) {
  long e = ((long)blockIdx.x * blockDim.x + threadIdx.x) * 8;
  const float* src;
  if (e < (long)BSD) src = q + e;
  else if (e < 2L*BSD) src = k + (e - (long)BSD);
  else if (e < 3L*BSD) src = v + (e - 2L*BSD);
  else {
    long r = e - 3L*BSD;
    if (r < (long)WSZ) src = wq + r;
    else if (r < 2L*WSZ) src = wk + (r - (long)WSZ);
    else if (r < 3L*WSZ) src = wv + (r - 2L*WSZ);
    else src = wd + (r - 3L*WSZ);
  }
  float4 f0 = ((const float4*)src)[0];
  float4 f1 = ((const float4*)src)[1];
  uint4 o;
  o.x = pack_bf16rn(f0.x, f0.y);
  o.y = pack_bf16rn(f0.z, f0.w);
  o.z = pack_bf16rn(f1.x, f1.y);
  o.w = pack_bf16rn(f1.z, f1.w);
  *(uint4*)(ws + e) = o;
}

// ---------------- C = A @ B^T (m97-style 128x128xBK32) ----------------
// MODE 0: bf16 C = val*oscale, row-major [M,N]
// MODE 1: f32  C = val + bias[c]
// MODE 2: bf16 written TRANSPOSED into Vt [B=4, H=12, 64, 2048] (packed 8B stores)
// BSEL 1: fused Q+K projection — rows >= 8192 use Bw+WSZ (wk) and scale 1
template<int MODE, int BSEL>
__global__ __launch_bounds__(256) void gemm_bt(const u16* __restrict__ A, const u16* __restrict__ Bw,
                                               u16* __restrict__ Cb, float* __restrict__ Cf,
                                               const float* __restrict__ bias,
                                               int M, int N, int K, float oscale) {
  __shared__ u16 ldsA[128*32];
  __shared__ u16 ldsB[128*32];
  const int t = threadIdx.x, w = t >> 6, lane = t & 63, quad = lane >> 4, n16 = lane & 15;
  const int m0 = blockIdx.x * 128, n0 = blockIdx.y * 128;
  const int wr = (w >> 1) * 64, wc = (w & 1) * 64;
  const u16* Bm = Bw;
  float sc = oscale;
  if (BSEL && m0 >= 8192) { Bm = Bw + WSZ; sc = 1.0f; }
  f32x4 acc[4][4] = {};
  for (int k0 = 0; k0 < K; k0 += 32) {
    __syncthreads();
#pragma unroll
    for (int j = 0; j < 2; ++j) {
      int slot = j*256 + w*64 + lane;        // lane-linear LDS dst
      int row = slot >> 2, ch = slot & 3;
      load_lds16(A  + (size_t)(m0 + row)*K + k0 + ch*8, ldsA + slot*8);
      load_lds16(Bm + (size_t)(n0 + row)*K + k0 + ch*8, ldsB + slot*8);
    }
    __syncthreads();
    bf16x8 af[4], bf[4];
#pragma unroll
    for (int i = 0; i < 4; ++i) {
      af[i] = *(const bf16x8*)(ldsA + (wr + i*16 + n16)*32 + quad*8);
      bf[i] = *(const bf16x8*)(ldsB + (wc + i*16 + n16)*32 + quad*8);
    }
#pragma unroll
    for (int mi = 0; mi < 4; ++mi)
#pragma unroll
      for (int ni = 0; ni < 4; ++ni)
        acc[mi][ni] = mfma16(af[mi], bf[ni], acc[mi][ni]);
  }
#pragma unroll
  for (int mi = 0; mi < 4; ++mi)
#pragma unroll
    for (int ni = 0; ni < 4; ++ni) {
      if (MODE == 2) {
        int c = n0 + wc + ni*16 + n16;                 // feature 0..767
        int hh = c >> 6, d = c & 63;
        int m = m0 + wr + mi*16 + quad*4;              // 4 consecutive tokens
        int bI = m >> 11, s = m & 2047;
        uint2 pk;
        pk.x = pack_bf16rn(acc[mi][ni][0], acc[mi][ni][1]);
        pk.y = pack_bf16rn(acc[mi][ni][2], acc[mi][ni][3]);
        *(uint2*)(Cb + ((size_t)(bI*12 + hh)*64 + d)*2048 + s) = pk;
      } else {
#pragma unroll
        for (int i = 0; i < 4; ++i) {
          size_t r = (size_t)m0 + wr + mi*16 + quad*4 + i;   // C/D: row=(lane>>4)*4+i
          size_t c = (size_t)n0 + wc + ni*16 + n16;          //      col=lane&15
          float val = acc[mi][ni][i];
          if (MODE == 1) Cf[r*(size_t)N + c] = val + bias[c];
          else           Cb[r*(size_t)N + c] = f2bf(val * sc);
        }
      }
    }
}

// ---------------- fused attention, round 3: dbuf staging + 1-inst exp + perm pack ----------------
// S^T = K.Q^T (operand swap) so each lane holds 4 consecutive n for fixed m:
// P stored row-major with ds_write_b64, ldsP wave-private, PV reads A-layout b128.
// K/V chunks double-buffered: prefetch c+1 issued right after the barrier that
// publishes chunk c, so the vmcnt(0)-at-barrier drain overlaps a full compute phase.
__global__ __launch_bounds__(256, 3) void attn_fused(const u16* __restrict__ Qh, const u16* __restrict__ Kh,
                                                     const u16* __restrict__ Vt, u16* __restrict__ ctx,
                                                     float* __restrict__ rowsum) {
  __shared__ u16 ldsK[2][64*64];   // [n][8 chunks of 8 u16], chunk XOR-swizzled by n&7
  __shared__ u16 ldsV[2][64*64];   // [d][8 chunks],          swizzled by d&7
  __shared__ u16 ldsP[128*64];     // [m][8 b128-chunks],     swizzled by m&7; wave-private rows
  const int qt = blockIdx.x, h = blockIdx.y, b = blockIdx.z;
  const int t = threadIdx.x, w = t >> 6, lane = t & 63, quad = lane >> 4, n16 = lane & 15;
  const int q0 = qt * 128;
  const int sw = n16 & 7;
  const u16* Kbh = Kh + (size_t)b*2048*768 + h*64;
  const u16* Vbh = Vt + (size_t)(b*12 + h)*64*2048;
  auto stage = [&](int c, int bsel) {
#pragma unroll
    for (int j = 0; j < 2; ++j) {
      int slot = j*256 + t;                 // lane-linear LDS dst
      int n = slot >> 3, cg = (slot & 7) ^ (n & 7);
      load_lds16(Kbh + (size_t)(c*64 + n)*768 + cg*8, &ldsK[bsel][0] + slot*8);
      load_lds16(Vbh + (size_t)n*2048 + c*64 + cg*8, &ldsV[bsel][0] + slot*8);
    }
  };
  bf16x8 qf[2][2];                 // Q frags (pre-scaled by log2e/8) in regs all kernel
#pragma unroll
  for (int mi = 0; mi < 2; ++mi)
#pragma unroll
    for (int ks = 0; ks < 2; ++ks)
      qf[mi][ks] = *(const bf16x8*)(Qh + (size_t)(b*2048 + q0 + w*32 + mi*16 + n16)*768
                                       + h*64 + ks*32 + quad*8);
  f32x4 oacc[2][4] = {};
  float rs[2] = {};
  stage(0, 0);
#pragma unroll 1
  for (int c = 0; c < 32; ++c) {
    __syncthreads();                        // chunk c staged (vmcnt drain); prior reads of buf[(c+1)&1] done
    if (c < 31) stage(c + 1, (c + 1) & 1);  // prefetch overlaps this chunk's compute
    const u16* K0 = &ldsK[c & 1][0];
    const u16* V0 = &ldsV[c & 1][0];
    f32x4 sacc[4][2] = {};
#pragma unroll
    for (int ni = 0; ni < 4; ++ni) {
      const u16* krow = K0 + (ni*16 + n16)*64;
      bf16x8 kf0 = *(const bf16x8*)(krow + ((0 + quad) ^ sw)*8);
      bf16x8 kf1 = *(const bf16x8*)(krow + ((4 + quad) ^ sw)*8);
#pragma unroll
      for (int mi = 0; mi < 2; ++mi) {
        sacc[ni][mi] = mfma16(kf0, qf[mi][0], sacc[ni][mi]);   // S^T = K.Q^T
        sacc[ni][mi] = mfma16(kf1, qf[mi][1], sacc[ni][mi]);
      }
    }
    // exp2 (Q pre-scaled -> 1 v_exp each) + perm-packed P store
#pragma unroll
    for (int mi = 0; mi < 2; ++mi) {
      int m = w*32 + mi*16 + n16;
      u16* prow = ldsP + m*64 + (quad & 1)*4;
#pragma unroll
      for (int ni = 0; ni < 4; ++ni) {
        float p0 = EXP2(sacc[ni][mi][0]);
        float p1 = EXP2(sacc[ni][mi][1]);
        float p2 = EXP2(sacc[ni][mi][2]);
        float p3 = EXP2(sacc[ni][mi][3]);
        rs[mi] += (p0 + p1) + (p2 + p3);
        uint2 pk;
        pk.x = pack_bf16rn(p0, p1);
        pk.y = pack_bf16rn(p2, p3);
        int c128 = ((ni*2 + (quad >> 1)) ^ sw);
        *(uint2*)(prow + c128*8) = pk;
      }
    }
    // PV: A = P (wave-private rows, no barrier), B = V^T chunk
#pragma unroll
    for (int kt = 0; kt < 2; ++kt) {
      bf16x8 pf[2], vf[4];
#pragma unroll
      for (int mi = 0; mi < 2; ++mi)
        pf[mi] = *(const bf16x8*)(ldsP + (w*32 + mi*16 + n16)*64 + ((kt*4 + quad) ^ sw)*8);
#pragma unroll
      for (int di = 0; di < 4; ++di)
        vf[di] = *(const bf16x8*)(V0 + (di*16 + n16)*64 + ((kt*4 + quad) ^ sw)*8);
#pragma unroll
      for (int mi = 0; mi < 2; ++mi)
#pragma unroll
        for (int di = 0; di < 4; ++di)
          oacc[mi][di] = mfma16(pf[mi], vf[di], oacc[mi][di]);
    }
  }
  // full row sums: reduce across the 4 quads (lanes sharing n16)
#pragma unroll
  for (int mi = 0; mi < 2; ++mi) {
    float s = rs[mi];
    s += __shfl_xor(s, 16);
    s += __shfl_xor(s, 32);
    rs[mi] = s;
  }
  // redistribute: oacc C-layout rows are quad*4+i; rowsum lives at lane n16==row
  float invr[2][4];
#pragma unroll
  for (int mi = 0; mi < 2; ++mi)
#pragma unroll
    for (int i = 0; i < 4; ++i)
      invr[mi][i] = 1.0f / __shfl(rs[mi], (lane & 48) | (quad*4 + i));
#pragma unroll
  for (int mi = 0; mi < 2; ++mi)
#pragma unroll
    for (int di = 0; di < 4; ++di)
#pragma unroll
      for (int i = 0; i < 4; ++i) {
        size_t r = (size_t)b*2048 + q0 + w*32 + mi*16 + quad*4 + i;
        int cc = h*64 + di*16 + n16;
        ctx[r*768 + cc] = f2bf(oacc[mi][di][i] * invr[mi][i]);
      }
  if (h == 0 && quad == 0) {
#pragma unroll
    for (int mi = 0; mi < 2; ++mi)
      rowsum[b*2048 + q0 + w*32 + mi*16 + n16] = rs[mi];
  }
}

// ---------------- attn[:,0,:,:]: recompute QK^T for h=0, scale by 1/rowsum ----------------
__global__ __launch_bounds__(256) void attn_h0(const u16* __restrict__ Qh, const u16* __restrict__ Kh,
                                               const float* __restrict__ rowsum, float* __restrict__ aout) {
  __shared__ u16 ldsK[128*64];
  const int qt = blockIdx.x, kt = blockIdx.y, b = blockIdx.z;
  const int t = threadIdx.x, w = t >> 6, lane = t & 63, quad = lane >> 4, n16 = lane & 15;
  const int q0 = qt * 128;
  const u16* Kbh = Kh + (size_t)b*2048*768;  // h = 0
  bf16x8 qf[2][2];
#pragma unroll
  for (int mi = 0; mi < 2; ++mi)
#pragma unroll
    for (int ks = 0; ks < 2; ++ks)
      qf[mi][ks] = *(const bf16x8*)(Qh + (size_t)(b*2048 + q0 + w*32 + mi*16 + n16)*768
                                       + ks*32 + quad*8);
#pragma unroll
  for (int j = 0; j < 4; ++j) {
    int slot = j*256 + w*64 + lane;
    int n = slot >> 3, cs = slot & 7, cg = cs ^ (n & 7);
    load_lds16(Kbh + (size_t)(kt*128 + n)*768 + cg*8, ldsK + slot*8);
  }
  __syncthreads();
  f32x4 sacc[2][8] = {};
#pragma unroll
  for (int ni = 0; ni < 8; ++ni) {
    int n = ni*16 + n16;
    bf16x8 kf0 = *(const bf16x8*)(ldsK + n*64 + ((quad)     ^ (n & 7))*8);
    bf16x8 kf1 = *(const bf16x8*)(ldsK + n*64 + ((4 + quad) ^ (n & 7))*8);
#pragma unroll
    for (int mi = 0; mi < 2; ++mi) {
      sacc[mi][ni] = mfma16(qf[mi][0], kf0, sacc[mi][ni]);
      sacc[mi][ni] = mfma16(qf[mi][1], kf1, sacc[mi][ni]);
    }
  }
  float inv[2][4];
#pragma unroll
  for (int mi = 0; mi < 2; ++mi)
#pragma unroll
    for (int i = 0; i < 4; ++i)
      inv[mi][i] = 1.0f / rowsum[b*2048 + q0 + w*32 + mi*16 + quad*4 + i];
#pragma unroll
  for (int mi = 0; mi < 2; ++mi)
#pragma unroll
    for (int ni = 0; ni < 8; ++ni)
#pragma unroll
      for (int i = 0; i < 4; ++i) {
        size_t r = (size_t)b*2048 + q0 + w*32 + mi*16 + quad*4 + i;
        size_t cc = (size_t)kt*128 + ni*16 + n16;
        aout[r*2048 + cc] = EXP2(sacc[mi][ni][i]) * inv[mi][i];   // Qh pre-scaled
      }
}

extern "C" void kernel_launch(void* const* d_in, const int* in_sizes, int n_in,
                              void* d_out, int out_size, void* d_ws, size_t ws_size,
                              hipStream_t stream) {
  (void)in_sizes; (void)n_in; (void)out_size; (void)ws_size;
  const float* q  = (const float*)d_in[0];
  const float* k  = (const float*)d_in[1];
  const float* v  = (const float*)d_in[2];
  const float* wq = (const float*)d_in[3];
  const float* wk = (const float*)d_in[4];
  const float* wv = (const float*)d_in[5];
  const float* wd = (const float*)d_in[6];
  const float* bd = (const float*)d_in[7];

  // ws layout (u16 elements), high-water ~67.7 MB:
  //   qb -> Vt   (qb dead after fused QK projection; V-gemm writes Vt there)
  //   kb -> ctx  (kb dead after fused QK projection)
  u16* ws  = (u16*)d_ws;
  u16* qb  = ws;                       // rows 0..8191  of fused QK A-matrix
  u16* kb  = ws + (size_t)BSD;         // rows 8192..16383
  u16* vb  = ws + 2L*BSD;
  u16* wqb = ws + 3L*BSD;              // wq, wk contiguous (BSEL indexing)
  u16* wvb = wqb + 2L*WSZ;
  u16* wdb = wqb + 3L*WSZ;
  u16* Qh  = ws + 3L*BSD + 4L*WSZ;     // Qh, Kh contiguous (fused QK C-matrix)
  u16* Kh  = Qh + (size_t)BSD;
  float* rsum = (float*)(Kh + (size_t)BSD);
  u16* Vt  = qb;
  u16* ctx = kb;
  float* out  = (float*)d_out;
  float* aout = out + (size_t)BSD;

  convert_all<<<dim3(10368), 256, 0, stream>>>(q, k, v, wq, wk, wv, wd, ws);
  // fused Q+K projection (Q pre-scaled by log2e/8), 768 blocks = 3/CU even
  gemm_bt<0,1><<<dim3(128, 6), 256, 0, stream>>>(qb, wqb, Qh, nullptr, nullptr, 16384, 768, 768, QSCALE);
  // V projection with fused transpose into Vt
  gemm_bt<2,0><<<dim3(64, 6), 256, 0, stream>>>(vb, wvb, Vt, nullptr, nullptr, 8192, 768, 768, 1.0f);
  attn_fused<<<dim3(16, 12, 4), 256, 0, stream>>>(Qh, Kh, Vt, ctx, rsum);
  attn_h0<<<dim3(16, 16, 4), 256, 0, stream>>>(Qh, Kh, rsum, aout);
  gemm_bt<1,0><<<dim3(64, 6), 256, 0, stream>>>(ctx, wdb, nullptr, out, bd, 8192, 768, 768, 1.0f);
}